// Round 17
// baseline (428.200 us; speedup 1.0000x reference)
//
#include <hip/hip_runtime.h>

// ---------------------------------------------------------------------------
// GCNModelWPathways: 3-layer GCN (N nodes, BS=8 batch, H=64) + committee
// pathway pooling + 2-layer MLP head + log_softmax.
//
// Structure: linear (register-tiled, per-slice, unroll-1 loop) -> agg (pull
// gather, per-slice, 4-node predicated-interleaved waves) x3, pathway + head.
//
// R17: agg predicated max-loop. R16's `while(all 4 chains)` + serial drains
// left ~25% of edges running 1-wide (Poisson-degree imbalance). Now: run
// max(steps) iterations; per chain the csr index is `pred ? csr[i] : 0`
// (wave-uniform cndmask; row-0 gathers are L1-hot), all 4 gathers issue
// unconditionally back-to-back (keeps 4 in flight), accumulate is
// select-predicated. Remainders (deg&3) unchanged.
//
// Register saga (linear): uncapped=240 VGPR/10% occ; capped w/o shrinking
// live set = spill; unroll-1 + (256,2) = honest fit (R15). NEVER cap below
// the live set. Kept: [R5] b = blockIdx % 8 XCD slice pinning. [R10/R11]
// fp32 features; u16 csr. [R8] csr NEVER nt. [R6] dinv prescale in linear.
// [R12] do NOT fuse agg+linear. [R3] macro params never named x/y/z/w.
// [R9] nt builtins need ext_vector_type.
// ---------------------------------------------------------------------------

using f4v = __attribute__((ext_vector_type(4))) float;

__global__ void count_kernel(const int* __restrict__ dst, int* __restrict__ degi, int E) {
  int e = blockIdx.x * blockDim.x + threadIdx.x;
  if (e < E) atomicAdd(&degi[dst[e]], 1);
}

// single-block exclusive prefix sum over counts[0..n) -> row_start[0..n]
__global__ void prefix_kernel(const int* __restrict__ counts, int* __restrict__ row_start, int n) {
  __shared__ int sums[1024];
  int t = threadIdx.x;
  int chunk = (n + 1023) >> 10;
  int beg = t * chunk;
  int end = min(beg + chunk, n);
  int s = 0;
  for (int i = beg; i < end; ++i) s += counts[i];
  sums[t] = s;
  __syncthreads();
  for (int d = 1; d < 1024; d <<= 1) {
    int v = (t >= d) ? sums[t - d] : 0;
    __syncthreads();
    sums[t] += v;
    __syncthreads();
  }
  int off = (t == 0) ? 0 : sums[t - 1];
  for (int i = beg; i < end; ++i) { row_start[i] = off; off += counts[i]; }
  if (end == n) row_start[n] = off;  // all such threads write the total
}

__global__ void fill_kernel(const int* __restrict__ src, const int* __restrict__ dst,
                            const int* __restrict__ row_start, int* __restrict__ cursor,
                            unsigned short* __restrict__ csr, int E) {
  int e = blockIdx.x * blockDim.x + threadIdx.x;
  if (e < E) {
    int d = dst[e];
    int pos = atomicAdd(&cursor[d], 1);
    csr[row_start[d] + pos] = (unsigned short)src[e];  // N < 65536
  }
}

__global__ void dinv_kernel(const int* __restrict__ degi, float* __restrict__ dinv, int N) {
  int n = blockIdx.x * blockDim.x + threadIdx.x;
  if (n < N) dinv[n] = rsqrtf((float)(degi[n] + 1));  // +1: self-loop
}

// Register-tiled linear on one b-slice:
//   ms[b][r][h] = dinv[r] * sum_f H[b][r][f] * W[h][f]
// Grid = ceil(N/64)*BS; b = blockIdx % BS (XCD-aligned); 256 threads;
// 64 rows x 64 h per block; 4x4 tile per thread in named float4 registers.
// unroll 1 keeps the live set ~80 VGPR; (256,2) is then honest (R15).
__global__ __launch_bounds__(256, 2)
void linear_kernel(const float* __restrict__ hin, const float* __restrict__ W,
                   const float* __restrict__ dinv, float* __restrict__ ms,
                   int N, int BS) {
  __shared__ __align__(16) float Xs[64][68];
  __shared__ __align__(16) float Wt[64][68];  // Wt[f][h]
  int t = threadIdx.x;
  int b = blockIdx.x % BS;
  int chunk = blockIdx.x / BS;
  int row0 = chunk * 64;                 // node index within slice
  int nrows = min(64, N - row0);
  size_t sbase = ((size_t)b * N + row0) * 64;

  // stage W transposed (coalesced read, scattered LDS write; once per block)
  for (int i = t; i < 4096; i += 256) {
    int h = i >> 6, f = i & 63;
    Wt[f][h] = W[i];
  }
  // stage X tile: 4 threads per row, each covers 4 float4s (stride 4)
  {
    int rr = t >> 2;   // 0..63
    int c0 = t & 3;
    bool valid = rr < nrows;
    const float* srcp = hin + sbase + (size_t)rr * 64;
#pragma unroll
    for (int c = 0; c < 4; ++c) {
      int f4 = c0 + c * 4;
      float4 v = valid ? reinterpret_cast<const float4*>(srcp)[f4]
                       : float4{0.f, 0.f, 0.f, 0.f};
      *reinterpret_cast<float4*>(&Xs[rr][4 * f4]) = v;
    }
  }
  __syncthreads();

  int hg = t & 15;   // h0 = 4*hg
  int rg = t >> 4;   // r0 = 4*rg
  int r0 = 4 * rg;

  float4 acc0 = {0.f, 0.f, 0.f, 0.f};
  float4 acc1 = {0.f, 0.f, 0.f, 0.f};
  float4 acc2 = {0.f, 0.f, 0.f, 0.f};
  float4 acc3 = {0.f, 0.f, 0.f, 0.f};

// NOTE: macro params must NOT be named x/y/z/w (round-3 compile failure).
#define FMA4(A, S, V)            \
  A.x = fmaf((S), (V).x, A.x);   \
  A.y = fmaf((S), (V).y, A.y);   \
  A.z = fmaf((S), (V).z, A.z);   \
  A.w = fmaf((S), (V).w, A.w);

#pragma unroll 1  // bound the live set: one iteration's staging (8 f4) only
  for (int i = 0; i < 16; ++i) {  // f0 = 4*i
    float4 xr0 = *reinterpret_cast<const float4*>(&Xs[r0 + 0][4 * i]);
    float4 xr1 = *reinterpret_cast<const float4*>(&Xs[r0 + 1][4 * i]);
    float4 xr2 = *reinterpret_cast<const float4*>(&Xs[r0 + 2][4 * i]);
    float4 xr3 = *reinterpret_cast<const float4*>(&Xs[r0 + 3][4 * i]);
    float4 wv0 = *reinterpret_cast<const float4*>(&Wt[4 * i + 0][4 * hg]);
    float4 wv1 = *reinterpret_cast<const float4*>(&Wt[4 * i + 1][4 * hg]);
    float4 wv2 = *reinterpret_cast<const float4*>(&Wt[4 * i + 2][4 * hg]);
    float4 wv3 = *reinterpret_cast<const float4*>(&Wt[4 * i + 3][4 * hg]);
    FMA4(acc0, xr0.x, wv0); FMA4(acc0, xr0.y, wv1); FMA4(acc0, xr0.z, wv2); FMA4(acc0, xr0.w, wv3);
    FMA4(acc1, xr1.x, wv0); FMA4(acc1, xr1.y, wv1); FMA4(acc1, xr1.z, wv2); FMA4(acc1, xr1.w, wv3);
    FMA4(acc2, xr2.x, wv0); FMA4(acc2, xr2.y, wv1); FMA4(acc2, xr2.z, wv2); FMA4(acc2, xr2.w, wv3);
    FMA4(acc3, xr3.x, wv0); FMA4(acc3, xr3.y, wv1); FMA4(acc3, xr3.z, wv2); FMA4(acc3, xr3.w, wv3);
  }
#undef FMA4

  // epilogue: scale by dinv[row] (pre-scaled gather operand), float4 store
#define STORE_S(A, RIDX)                                                   \
  if ((RIDX) < nrows) {                                                    \
    float d = dinv[row0 + (RIDX)];                                         \
    float4 o = {A.x * d, A.y * d, A.z * d, A.w * d};                       \
    reinterpret_cast<float4*>(&ms[sbase + (size_t)(RIDX) * 64])[hg] = o;   \
  }
  STORE_S(acc0, r0 + 0)
  STORE_S(acc1, r0 + 1)
  STORE_S(acc2, r0 + 2)
  STORE_S(acc3, r0 + 3)
#undef STORE_S
}

// Pull aggregation on one b-slice. Grid = ceil(N/32)*BS; b = blockIdx % BS.
// Block = 512 threads = 8 waves; each wave owns FOUR nodes. R17: single
// predicated max-steps loop — all 4 gathers issue every iteration (index
// cndmask'd to row 0 when a chain is done; row-0 reads are L1-hot), adds are
// select-predicated. Keeps 4 chains in flight through the degree-imbalance
// tail that R16 drained serially. eg = lane>>4 (edge slot), hq = lane&15.
template <bool WRITE_H>
__global__ void agg_kernel(const float* __restrict__ ms, const float* __restrict__ dinv,
                           const float* __restrict__ bias, const int* __restrict__ row_start,
                           const unsigned short* __restrict__ csr, float* __restrict__ hout,
                           float* __restrict__ q, const float* __restrict__ fcw,
                           int layer, int L, int N, int BS) {
  int b = blockIdx.x % BS;
  int chunk = blockIdx.x / BS;
  int wv = threadIdx.x >> 6, lane = threadIdx.x & 63;
  int nA = chunk * 32 + 4 * wv;
  if (nA >= N) return;
  int nB = nA + 1, nC = nA + 2, nD = nA + 3;
  bool okB = nB < N, okC = nC < N, okD = nD < N;
  int eg = lane >> 4;     // edge slot 0..3
  int hq = lane & 15;     // h quad: h = 4*hq .. 4*hq+3
  size_t bN = (size_t)b * N;
  const float* mb = ms + bN * 64;

  f4v accA = {0.f, 0.f, 0.f, 0.f};
  f4v accB = {0.f, 0.f, 0.f, 0.f};
  f4v accC = {0.f, 0.f, 0.f, 0.f};
  f4v accD = {0.f, 0.f, 0.f, 0.f};
  // self-loops (counted once — eg 0 only)
  if (eg == 0) {
    accA = *reinterpret_cast<const f4v*>(mb + (size_t)nA * 64 + 4 * hq);
    if (okB) accB = *reinterpret_cast<const f4v*>(mb + (size_t)nB * 64 + 4 * hq);
    if (okC) accC = *reinterpret_cast<const f4v*>(mb + (size_t)nC * 64 + 4 * hq);
    if (okD) accD = *reinterpret_cast<const f4v*>(mb + (size_t)nD * 64 + 4 * hq);
  }

  int begA = row_start[nA], endA = row_start[nA + 1];
  int begB = begA, endB = begA, begC = begA, endC = begA, begD = begA, endD = begA;
  if (okB) { begB = row_start[nB]; endB = row_start[nB + 1]; }
  if (okC) { begC = row_start[nC]; endC = row_start[nC + 1]; }
  if (okD) { begD = row_start[nD]; endD = row_start[nD + 1]; }
  int stA = (endA - begA) >> 2;   // full 4-edge steps per chain
  int stB = (endB - begB) >> 2;
  int stC = (endC - begC) >> 2;
  int stD = (endD - begD) >> 2;
  int maxSt = max(max(stA, stB), max(stC, stD));

  // predicated interleaved loop: 4 gathers in flight every iteration
  for (int s = 0; s < maxSt; ++s) {
    bool pA = s < stA, pB = s < stB, pC = s < stC, pD = s < stD;
    int sa = pA ? (int)csr[begA + 4 * s + eg] : 0;
    int sb = pB ? (int)csr[begB + 4 * s + eg] : 0;
    int sc = pC ? (int)csr[begC + 4 * s + eg] : 0;
    int sd = pD ? (int)csr[begD + 4 * s + eg] : 0;
    f4v va = *reinterpret_cast<const f4v*>(mb + (size_t)sa * 64 + 4 * hq);
    f4v vb = *reinterpret_cast<const f4v*>(mb + (size_t)sb * 64 + 4 * hq);
    f4v vc = *reinterpret_cast<const f4v*>(mb + (size_t)sc * 64 + 4 * hq);
    f4v vd = *reinterpret_cast<const f4v*>(mb + (size_t)sd * 64 + 4 * hq);
    f4v z = {0.f, 0.f, 0.f, 0.f};
    accA += pA ? va : z;
    accB += pB ? vb : z;
    accC += pC ? vc : z;
    accD += pD ? vd : z;
  }
  // remainders (0..3 edges each)
#define REMD(ACC, BEGI, STI, ENDI)                                           \
  {                                                                          \
    int i_ = (BEGI) + 4 * (STI);                                             \
    int rem_ = (ENDI) - i_;                                                  \
    if (rem_ > 0) {                                                          \
      int e_ = i_ + ((eg < rem_) ? eg : 0);                                  \
      int s_ = csr[e_];                                                      \
      f4v v_ = *reinterpret_cast<const f4v*>(mb + (size_t)s_ * 64 + 4 * hq); \
      if (eg < rem_) (ACC) += v_;                                            \
    }                                                                        \
  }
  REMD(accA, begA, stA, endA)
  REMD(accB, begB, stB, endB)
  REMD(accC, begC, stC, endC)
  REMD(accD, begD, stD, endD)
#undef REMD

  // reduce across the 4 edge-slot groups (lanes differing in bits 4,5)
#define RED(ACC)                                              \
  (ACC).x += __shfl_xor((ACC).x, 16); (ACC).y += __shfl_xor((ACC).y, 16);  \
  (ACC).z += __shfl_xor((ACC).z, 16); (ACC).w += __shfl_xor((ACC).w, 16);  \
  (ACC).x += __shfl_xor((ACC).x, 32); (ACC).y += __shfl_xor((ACC).y, 32);  \
  (ACC).z += __shfl_xor((ACC).z, 32); (ACC).w += __shfl_xor((ACC).w, 32);
  RED(accA) RED(accB) RED(accC) RED(accD)
#undef RED

  float4 bias4 = *reinterpret_cast<const float4*>(&bias[4 * hq]);
  int h0 = 4 * hq;
  float fw0 = fcw[(h0 + 0) * L + layer];
  float fw1 = fcw[(h0 + 1) * L + layer];
  float fw2 = fcw[(h0 + 2) * L + layer];
  float fw3 = fcw[(h0 + 3) * L + layer];

#define FINISH(ACC, NODE, OK)                                                  \
  {                                                                            \
    float dn_ = (OK) ? dinv[NODE] : 0.f;                                       \
    f4v val_;                                                                  \
    val_.x = fmaxf(fmaf(dn_, (ACC).x, bias4.x), 0.f);                          \
    val_.y = fmaxf(fmaf(dn_, (ACC).y, bias4.y), 0.f);                          \
    val_.z = fmaxf(fmaf(dn_, (ACC).z, bias4.z), 0.f);                          \
    val_.w = fmaxf(fmaf(dn_, (ACC).w, bias4.w), 0.f);                          \
    if (WRITE_H && eg == 0 && (OK))                                            \
      __builtin_nontemporal_store(val_,                                        \
          reinterpret_cast<f4v*>(hout + bN * 64 + (size_t)(NODE) * 64 + 4 * hq)); \
    float qp_ = val_.x * fw0 + val_.y * fw1 + val_.z * fw2 + val_.w * fw3;     \
    qp_ += __shfl_xor(qp_, 1); qp_ += __shfl_xor(qp_, 2);                      \
    qp_ += __shfl_xor(qp_, 4); qp_ += __shfl_xor(qp_, 8);                      \
    if (lane == 0 && (OK)) {                                                   \
      if (layer == 0) q[bN + (NODE)] = qp_;                                    \
      else q[bN + (NODE)] += qp_;                                              \
    }                                                                          \
  }
  FINISH(accA, nA, true)
  FINISH(accB, nB, okB)
  FINISH(accC, nC, okC)
  FINISH(accD, nD, okD)
#undef FINISH
}

__global__ void pathway_kernel(const int* __restrict__ row, const int* __restrict__ col,
                               const float* __restrict__ q, float* __restrict__ s_sum,
                               float* __restrict__ cntc, int R, int N, int BS) {
  int idx = blockIdx.x * blockDim.x + threadIdx.x;
  if (idx >= R * BS) return;
  int r = idx / BS, b = idx - (idx / BS) * BS;
  int c = col[r], nd = row[r];
  atomicAdd(&s_sum[c * BS + b], q[(size_t)b * N + nd]);
  if (b == 0) atomicAdd(&cntc[c], 1.0f);
}

__global__ void head_kernel(const float* __restrict__ s_sum, const float* __restrict__ cntc,
                            const float* __restrict__ fcb, const float* __restrict__ l1w,
                            const float* __restrict__ l1b, const float* __restrict__ l2w,
                            const float* __restrict__ l2b, float* __restrict__ out,
                            int NCMT, int HFC, int NCLS, int BS) {
  int b = blockIdx.x;
  __shared__ float sbuf[400];
  __shared__ float z1[200];
  __shared__ float z2[8];
  int t = threadIdx.x;  // 256
  for (int c = t; c < NCMT; c += 256) {
    float cn = fmaxf(cntc[c], 1.0f);
    sbuf[c] = s_sum[c * BS + b] / cn + fcb[0];
  }
  __syncthreads();
  for (int j = t; j < HFC; j += 256) {
    float a = l1b[j];
    for (int c = 0; c < NCMT; ++c) a = fmaf(sbuf[c], l1w[j * NCMT + c], a);
    z1[j] = fmaxf(a, 0.f);
  }
  __syncthreads();
  if (t < NCLS) {
    float a = l2b[t];
    for (int j = 0; j < HFC; ++j) a = fmaf(z1[j], l2w[t * HFC + j], a);
    z2[t] = a;
  }
  __syncthreads();
  if (t == 0) {
    float mx = z2[0];
    for (int k = 1; k < NCLS; ++k) mx = fmaxf(mx, z2[k]);
    float se = 0.f;
    for (int k = 0; k < NCLS; ++k) se += expf(z2[k] - mx);
    float lse = mx + logf(se);
    for (int k = 0; k < NCLS; ++k) out[b * NCLS + k] = z2[k] - lse;
  }
}

extern "C" void kernel_launch(void* const* d_in, const int* in_sizes, int n_in,
                              void* d_out, int out_size, void* d_ws, size_t ws_size,
                              hipStream_t stream) {
  const float* x   = (const float*)d_in[0];
  const int*  ei   = (const int*)d_in[2];
  const int*  row  = (const int*)d_in[3];
  const int*  col  = (const int*)d_in[4];
  const float* W1  = (const float*)d_in[5];
  const float* b1  = (const float*)d_in[6];
  const float* W2  = (const float*)d_in[7];
  const float* b2  = (const float*)d_in[8];
  const float* W3  = (const float*)d_in[9];
  const float* b3  = (const float*)d_in[10];
  const float* fcw = (const float*)d_in[11];
  const float* fcb = (const float*)d_in[12];
  const float* l1w = (const float*)d_in[13];
  const float* l1b = (const float*)d_in[14];
  const float* l2w = (const float*)d_in[15];
  const float* l2b = (const float*)d_in[16];

  const int BS   = in_sizes[1];               // 8
  const int H    = in_sizes[6];               // 64
  const int F    = in_sizes[5] / H;           // 64
  const int N    = in_sizes[0] / (BS * F);    // 15135
  const int E    = in_sizes[2] / 2;           // 300000
  const int R    = in_sizes[3];               // 40000
  const int HFC  = in_sizes[14];              // 200
  const int NCMT = in_sizes[13] / HFC;        // 400
  const int NCLS = in_sizes[16];              // 2
  const int L    = in_sizes[11] / H;          // 3

  // workspace carve-out (256B aligned)
  char* p = (char*)d_ws;
  auto alloc = [&](size_t bytes) {
    void* r = (void*)p;
    p += (bytes + 255) & ~(size_t)255;
    return r;
  };
  int*   degi      = (int*)alloc((size_t)N * 4);
  int*   cursor    = (int*)alloc((size_t)N * 4);
  int*   row_start = (int*)alloc((size_t)(N + 1) * 4);
  unsigned short* csr = (unsigned short*)alloc((size_t)(E + 8) * 2);  // u16 + pad
  float* dinv      = (float*)alloc((size_t)N * 4);
  float* q         = (float*)alloc((size_t)N * BS * 4);
  float* s_sum     = (float*)alloc((size_t)NCMT * BS * 4);
  float* cntc      = (float*)alloc((size_t)NCMT * 4);
  float* m         = (float*)alloc((size_t)N * BS * H * 4);
  float* hA        = (float*)alloc((size_t)N * BS * H * 4);
  float* hB        = (float*)alloc((size_t)N * BS * H * 4);

  (void)hipMemsetAsync(degi, 0, (size_t)N * 4, stream);
  (void)hipMemsetAsync(cursor, 0, (size_t)N * 4, stream);
  (void)hipMemsetAsync(csr + E, 0, 16, stream);  // zero the pad
  (void)hipMemsetAsync(s_sum, 0, (size_t)NCMT * BS * 4, stream);
  (void)hipMemsetAsync(cntc, 0, (size_t)NCMT * 4, stream);

  const int* e_src = ei;
  const int* e_dst = ei + E;

  count_kernel<<<(E + 255) / 256, 256, 0, stream>>>(e_dst, degi, E);
  prefix_kernel<<<1, 1024, 0, stream>>>(degi, row_start, N);
  fill_kernel<<<(E + 255) / 256, 256, 0, stream>>>(e_src, e_dst, row_start, cursor, csr, E);
  dinv_kernel<<<(N + 255) / 256, 256, 0, stream>>>(degi, dinv, N);

  int lin_grid = ((N + 63) / 64) * BS;   // b = blockIdx % BS -> XCD-pinned slices
  int agg_grid = ((N + 31) / 32) * BS;   // 8 waves x 4 nodes = 32 nodes/block
  int agg_threads = 512;

  // layer 1 (x is fp32 [b][n][f])
  linear_kernel<<<lin_grid, 256, 0, stream>>>(x, W1, dinv, m, N, BS);
  agg_kernel<true><<<agg_grid, agg_threads, 0, stream>>>(m, dinv, b1, row_start, csr, hA, q, fcw, 0, L, N, BS);
  // layer 2
  linear_kernel<<<lin_grid, 256, 0, stream>>>(hA, W2, dinv, m, N, BS);
  agg_kernel<true><<<agg_grid, agg_threads, 0, stream>>>(m, dinv, b2, row_start, csr, hB, q, fcw, 1, L, N, BS);
  // layer 3 — hout is dead (only q survives), skip the store
  linear_kernel<<<lin_grid, 256, 0, stream>>>(hB, W3, dinv, m, N, BS);
  agg_kernel<false><<<agg_grid, agg_threads, 0, stream>>>(m, dinv, b3, row_start, csr, nullptr, q, fcw, 2, L, N, BS);

  pathway_kernel<<<((size_t)R * BS + 255) / 256, 256, 0, stream>>>(row, col, q, s_sum, cntc, R, N, BS);
  head_kernel<<<BS, 256, 0, stream>>>(s_sum, cntc, fcb, l1w, l1b, l2w, l2b,
                                      (float*)d_out, NCMT, HFC, NCLS, BS);
}

// Round 18
// 363.841 us; speedup vs baseline: 1.1769x; 1.1769x over previous
//
#include <hip/hip_runtime.h>

// ---------------------------------------------------------------------------
// GCNModelWPathways: 3-layer GCN (N nodes, BS=8 batch, H=64) + committee
// pathway pooling + 2-layer MLP head + log_softmax.
//
// Structure: linear (register-tiled, per-slice, unroll-1 loop, 2 row-tiles
// per block) -> agg (pull gather, per-slice, 4-node interleaved waves) x3,
// then pathway + head.
//
// R18: agg reverted to R16 (predicated max-loop of R17 REGRESSED: issued
// ~30% more gather instrs incl. dead row-0 ones + occupancy 60->47%).
// Linear: two 64-row tiles per block, staging Wt once (halves the per-block
// 16KB W-stage fixed cost and the grid).
//
// Register saga (linear): uncapped=240 VGPR/10% occ; capped w/o shrinking
// live set = spill; unroll-1 + (256,2) = honest fit (R15). NEVER cap below
// the live set. Kept: [R5] b = blockIdx % 8 XCD slice pinning. [R10/R11]
// fp32 features; u16 csr. [R8] csr NEVER nt. [R6] dinv prescale in linear.
// [R12] do NOT fuse agg+linear. [R3] macro params never named x/y/z/w.
// [R9] nt builtins need ext_vector_type.
// ---------------------------------------------------------------------------

using f4v = __attribute__((ext_vector_type(4))) float;

__global__ void count_kernel(const int* __restrict__ dst, int* __restrict__ degi, int E) {
  int e = blockIdx.x * blockDim.x + threadIdx.x;
  if (e < E) atomicAdd(&degi[dst[e]], 1);
}

// single-block exclusive prefix sum over counts[0..n) -> row_start[0..n]
__global__ void prefix_kernel(const int* __restrict__ counts, int* __restrict__ row_start, int n) {
  __shared__ int sums[1024];
  int t = threadIdx.x;
  int chunk = (n + 1023) >> 10;
  int beg = t * chunk;
  int end = min(beg + chunk, n);
  int s = 0;
  for (int i = beg; i < end; ++i) s += counts[i];
  sums[t] = s;
  __syncthreads();
  for (int d = 1; d < 1024; d <<= 1) {
    int v = (t >= d) ? sums[t - d] : 0;
    __syncthreads();
    sums[t] += v;
    __syncthreads();
  }
  int off = (t == 0) ? 0 : sums[t - 1];
  for (int i = beg; i < end; ++i) { row_start[i] = off; off += counts[i]; }
  if (end == n) row_start[n] = off;  // all such threads write the total
}

__global__ void fill_kernel(const int* __restrict__ src, const int* __restrict__ dst,
                            const int* __restrict__ row_start, int* __restrict__ cursor,
                            unsigned short* __restrict__ csr, int E) {
  int e = blockIdx.x * blockDim.x + threadIdx.x;
  if (e < E) {
    int d = dst[e];
    int pos = atomicAdd(&cursor[d], 1);
    csr[row_start[d] + pos] = (unsigned short)src[e];  // N < 65536
  }
}

__global__ void dinv_kernel(const int* __restrict__ degi, float* __restrict__ dinv, int N) {
  int n = blockIdx.x * blockDim.x + threadIdx.x;
  if (n < N) dinv[n] = rsqrtf((float)(degi[n] + 1));  // +1: self-loop
}

// Register-tiled linear on one b-slice:
//   ms[b][r][h] = dinv[r] * sum_f H[b][r][f] * W[h][f]
// Grid = ceil(N/128)*BS; b = blockIdx % BS (XCD-aligned); 256 threads;
// TWO 64-row x 64-h tiles per block (Wt staged once); 4x4 tile per thread
// in named float4 registers. unroll-1 bounds the live set (R15); (256,2).
__global__ __launch_bounds__(256, 2)
void linear_kernel(const float* __restrict__ hin, const float* __restrict__ W,
                   const float* __restrict__ dinv, float* __restrict__ ms,
                   int N, int BS) {
  __shared__ __align__(16) float Xs[64][68];
  __shared__ __align__(16) float Wt[64][68];  // Wt[f][h]
  int t = threadIdx.x;
  int b = blockIdx.x % BS;
  int chunk = blockIdx.x / BS;
  size_t bN64 = (size_t)b * N * 64;

  // stage W transposed once per block
  for (int i = t; i < 4096; i += 256) {
    int h = i >> 6, f = i & 63;
    Wt[f][h] = W[i];
  }

  int hg = t & 15;   // h0 = 4*hg
  int rg = t >> 4;   // r0 = 4*rg
  int r0 = 4 * rg;
  int xr_row = t >> 2;   // X-stage: 4 threads per row
  int xr_c0 = t & 3;

// NOTE: macro params must NOT be named x/y/z/w (round-3 compile failure).
#define FMA4(A, S, V)            \
  A.x = fmaf((S), (V).x, A.x);   \
  A.y = fmaf((S), (V).y, A.y);   \
  A.z = fmaf((S), (V).z, A.z);   \
  A.w = fmaf((S), (V).w, A.w);

#pragma unroll 1
  for (int tile = 0; tile < 2; ++tile) {
    int row0 = chunk * 128 + tile * 64;
    if (row0 >= N) break;
    int nrows = min(64, N - row0);
    size_t sbase = bN64 + (size_t)row0 * 64;

    __syncthreads();  // Wt ready (tile 0) / previous-tile reads done (tile 1)
    // stage X tile
    {
      bool valid = xr_row < nrows;
      const float* srcp = hin + sbase + (size_t)xr_row * 64;
#pragma unroll
      for (int c = 0; c < 4; ++c) {
        int f4 = xr_c0 + c * 4;
        float4 v = valid ? reinterpret_cast<const float4*>(srcp)[f4]
                         : float4{0.f, 0.f, 0.f, 0.f};
        *reinterpret_cast<float4*>(&Xs[xr_row][4 * f4]) = v;
      }
    }
    __syncthreads();

    float4 acc0 = {0.f, 0.f, 0.f, 0.f};
    float4 acc1 = {0.f, 0.f, 0.f, 0.f};
    float4 acc2 = {0.f, 0.f, 0.f, 0.f};
    float4 acc3 = {0.f, 0.f, 0.f, 0.f};

#pragma unroll 1  // bound the live set: one iteration's staging (8 f4) only
    for (int i = 0; i < 16; ++i) {  // f0 = 4*i
      float4 xr0 = *reinterpret_cast<const float4*>(&Xs[r0 + 0][4 * i]);
      float4 xr1 = *reinterpret_cast<const float4*>(&Xs[r0 + 1][4 * i]);
      float4 xr2 = *reinterpret_cast<const float4*>(&Xs[r0 + 2][4 * i]);
      float4 xr3 = *reinterpret_cast<const float4*>(&Xs[r0 + 3][4 * i]);
      float4 wv0 = *reinterpret_cast<const float4*>(&Wt[4 * i + 0][4 * hg]);
      float4 wv1 = *reinterpret_cast<const float4*>(&Wt[4 * i + 1][4 * hg]);
      float4 wv2 = *reinterpret_cast<const float4*>(&Wt[4 * i + 2][4 * hg]);
      float4 wv3 = *reinterpret_cast<const float4*>(&Wt[4 * i + 3][4 * hg]);
      FMA4(acc0, xr0.x, wv0); FMA4(acc0, xr0.y, wv1); FMA4(acc0, xr0.z, wv2); FMA4(acc0, xr0.w, wv3);
      FMA4(acc1, xr1.x, wv0); FMA4(acc1, xr1.y, wv1); FMA4(acc1, xr1.z, wv2); FMA4(acc1, xr1.w, wv3);
      FMA4(acc2, xr2.x, wv0); FMA4(acc2, xr2.y, wv1); FMA4(acc2, xr2.z, wv2); FMA4(acc2, xr2.w, wv3);
      FMA4(acc3, xr3.x, wv0); FMA4(acc3, xr3.y, wv1); FMA4(acc3, xr3.z, wv2); FMA4(acc3, xr3.w, wv3);
    }

    // epilogue: scale by dinv[row] (pre-scaled gather operand), float4 store
#define STORE_S(A, RIDX)                                                   \
    if ((RIDX) < nrows) {                                                  \
      float d = dinv[row0 + (RIDX)];                                       \
      float4 o = {A.x * d, A.y * d, A.z * d, A.w * d};                     \
      reinterpret_cast<float4*>(&ms[sbase + (size_t)(RIDX) * 64])[hg] = o; \
    }
    STORE_S(acc0, r0 + 0)
    STORE_S(acc1, r0 + 1)
    STORE_S(acc2, r0 + 2)
    STORE_S(acc3, r0 + 3)
#undef STORE_S
  }
#undef FMA4
}

// Pull aggregation on one b-slice. Grid = ceil(N/32)*BS; b = blockIdx % BS.
// Block = 512 threads = 8 waves; each wave owns FOUR nodes with interleaved
// gather chains (R16: 4 independent 256B gathers in flight per wave).
// Lane remap: eg = lane>>4 (edge slot 0..3), hq = lane&15 (h quad);
// u16 csr indices (L2-cached, NOT nt). fp32 accumulate.
template <bool WRITE_H>
__global__ void agg_kernel(const float* __restrict__ ms, const float* __restrict__ dinv,
                           const float* __restrict__ bias, const int* __restrict__ row_start,
                           const unsigned short* __restrict__ csr, float* __restrict__ hout,
                           float* __restrict__ q, const float* __restrict__ fcw,
                           int layer, int L, int N, int BS) {
  int b = blockIdx.x % BS;
  int chunk = blockIdx.x / BS;
  int wv = threadIdx.x >> 6, lane = threadIdx.x & 63;
  int nA = chunk * 32 + 4 * wv;
  if (nA >= N) return;
  int nB = nA + 1, nC = nA + 2, nD = nA + 3;
  bool okB = nB < N, okC = nC < N, okD = nD < N;
  int eg = lane >> 4;     // edge slot 0..3
  int hq = lane & 15;     // h quad: h = 4*hq .. 4*hq+3
  size_t bN = (size_t)b * N;
  const float* mb = ms + bN * 64;

  f4v accA = {0.f, 0.f, 0.f, 0.f};
  f4v accB = {0.f, 0.f, 0.f, 0.f};
  f4v accC = {0.f, 0.f, 0.f, 0.f};
  f4v accD = {0.f, 0.f, 0.f, 0.f};
  // self-loops (counted once — eg 0 only)
  if (eg == 0) {
    accA = *reinterpret_cast<const f4v*>(mb + (size_t)nA * 64 + 4 * hq);
    if (okB) accB = *reinterpret_cast<const f4v*>(mb + (size_t)nB * 64 + 4 * hq);
    if (okC) accC = *reinterpret_cast<const f4v*>(mb + (size_t)nC * 64 + 4 * hq);
    if (okD) accD = *reinterpret_cast<const f4v*>(mb + (size_t)nD * 64 + 4 * hq);
  }

  int begA = row_start[nA], endA = row_start[nA + 1];
  int begB = begA, endB = begA, begC = begA, endC = begA, begD = begA, endD = begA;
  if (okB) { begB = row_start[nB]; endB = row_start[nB + 1]; }
  if (okC) { begC = row_start[nC]; endC = row_start[nC + 1]; }
  if (okD) { begD = row_start[nD]; endD = row_start[nD + 1]; }
  int ia = begA, ib = begB, ic = begC, id = begD;
  int mA = begA + ((endA - begA) & ~3);
  int mB = begB + ((endB - begB) & ~3);
  int mC = begC + ((endC - begC) & ~3);
  int mD = begD + ((endD - begD) & ~3);

  // quad interleaved main loop: 4 independent gather chains in flight
  while (ia < mA && ib < mB && ic < mC && id < mD) {
    int sa = csr[ia + eg];
    int sb = csr[ib + eg];
    int sc = csr[ic + eg];
    int sd = csr[id + eg];
    f4v va = *reinterpret_cast<const f4v*>(mb + (size_t)sa * 64 + 4 * hq);
    f4v vb = *reinterpret_cast<const f4v*>(mb + (size_t)sb * 64 + 4 * hq);
    f4v vc = *reinterpret_cast<const f4v*>(mb + (size_t)sc * 64 + 4 * hq);
    f4v vd = *reinterpret_cast<const f4v*>(mb + (size_t)sd * 64 + 4 * hq);
    accA += va; accB += vb; accC += vc; accD += vd;
    ia += 4; ib += 4; ic += 4; id += 4;
  }
  // drain remaining full steps per chain
#define DRAIN(ACC, I, M)                                                     \
  while ((I) < (M)) {                                                        \
    int s_ = csr[(I) + eg];                                                  \
    (ACC) += *reinterpret_cast<const f4v*>(mb + (size_t)s_ * 64 + 4 * hq);   \
    (I) += 4;                                                                \
  }
  DRAIN(accA, ia, mA)
  DRAIN(accB, ib, mB)
  DRAIN(accC, ic, mC)
  DRAIN(accD, id, mD)
#undef DRAIN
  // remainders (0..3 edges each)
#define REMD(ACC, I, END)                                                    \
  {                                                                          \
    int rem_ = (END) - (I);                                                  \
    if (rem_ > 0) {                                                          \
      int e_ = (I) + ((eg < rem_) ? eg : 0);                                 \
      int s_ = csr[e_];                                                      \
      f4v v_ = *reinterpret_cast<const f4v*>(mb + (size_t)s_ * 64 + 4 * hq); \
      if (eg < rem_) (ACC) += v_;                                            \
    }                                                                        \
  }
  REMD(accA, ia, endA)
  REMD(accB, ib, endB)
  REMD(accC, ic, endC)
  REMD(accD, id, endD)
#undef REMD

  // reduce across the 4 edge-slot groups (lanes differing in bits 4,5)
#define RED(ACC)                                              \
  (ACC).x += __shfl_xor((ACC).x, 16); (ACC).y += __shfl_xor((ACC).y, 16);  \
  (ACC).z += __shfl_xor((ACC).z, 16); (ACC).w += __shfl_xor((ACC).w, 16);  \
  (ACC).x += __shfl_xor((ACC).x, 32); (ACC).y += __shfl_xor((ACC).y, 32);  \
  (ACC).z += __shfl_xor((ACC).z, 32); (ACC).w += __shfl_xor((ACC).w, 32);
  RED(accA) RED(accB) RED(accC) RED(accD)
#undef RED

  float4 bias4 = *reinterpret_cast<const float4*>(&bias[4 * hq]);
  int h0 = 4 * hq;
  float fw0 = fcw[(h0 + 0) * L + layer];
  float fw1 = fcw[(h0 + 1) * L + layer];
  float fw2 = fcw[(h0 + 2) * L + layer];
  float fw3 = fcw[(h0 + 3) * L + layer];

#define FINISH(ACC, NODE, OK)                                                  \
  {                                                                            \
    float dn_ = (OK) ? dinv[NODE] : 0.f;                                       \
    f4v val_;                                                                  \
    val_.x = fmaxf(fmaf(dn_, (ACC).x, bias4.x), 0.f);                          \
    val_.y = fmaxf(fmaf(dn_, (ACC).y, bias4.y), 0.f);                          \
    val_.z = fmaxf(fmaf(dn_, (ACC).z, bias4.z), 0.f);                          \
    val_.w = fmaxf(fmaf(dn_, (ACC).w, bias4.w), 0.f);                          \
    if (WRITE_H && eg == 0 && (OK))                                            \
      __builtin_nontemporal_store(val_,                                        \
          reinterpret_cast<f4v*>(hout + bN * 64 + (size_t)(NODE) * 64 + 4 * hq)); \
    float qp_ = val_.x * fw0 + val_.y * fw1 + val_.z * fw2 + val_.w * fw3;     \
    qp_ += __shfl_xor(qp_, 1); qp_ += __shfl_xor(qp_, 2);                      \
    qp_ += __shfl_xor(qp_, 4); qp_ += __shfl_xor(qp_, 8);                      \
    if (lane == 0 && (OK)) {                                                   \
      if (layer == 0) q[bN + (NODE)] = qp_;                                    \
      else q[bN + (NODE)] += qp_;                                              \
    }                                                                          \
  }
  FINISH(accA, nA, true)
  FINISH(accB, nB, okB)
  FINISH(accC, nC, okC)
  FINISH(accD, nD, okD)
#undef FINISH
}

__global__ void pathway_kernel(const int* __restrict__ row, const int* __restrict__ col,
                               const float* __restrict__ q, float* __restrict__ s_sum,
                               float* __restrict__ cntc, int R, int N, int BS) {
  int idx = blockIdx.x * blockDim.x + threadIdx.x;
  if (idx >= R * BS) return;
  int r = idx / BS, b = idx - (idx / BS) * BS;
  int c = col[r], nd = row[r];
  atomicAdd(&s_sum[c * BS + b], q[(size_t)b * N + nd]);
  if (b == 0) atomicAdd(&cntc[c], 1.0f);
}

__global__ void head_kernel(const float* __restrict__ s_sum, const float* __restrict__ cntc,
                            const float* __restrict__ fcb, const float* __restrict__ l1w,
                            const float* __restrict__ l1b, const float* __restrict__ l2w,
                            const float* __restrict__ l2b, float* __restrict__ out,
                            int NCMT, int HFC, int NCLS, int BS) {
  int b = blockIdx.x;
  __shared__ float sbuf[400];
  __shared__ float z1[200];
  __shared__ float z2[8];
  int t = threadIdx.x;  // 256
  for (int c = t; c < NCMT; c += 256) {
    float cn = fmaxf(cntc[c], 1.0f);
    sbuf[c] = s_sum[c * BS + b] / cn + fcb[0];
  }
  __syncthreads();
  for (int j = t; j < HFC; j += 256) {
    float a = l1b[j];
    for (int c = 0; c < NCMT; ++c) a = fmaf(sbuf[c], l1w[j * NCMT + c], a);
    z1[j] = fmaxf(a, 0.f);
  }
  __syncthreads();
  if (t < NCLS) {
    float a = l2b[t];
    for (int j = 0; j < HFC; ++j) a = fmaf(z1[j], l2w[t * HFC + j], a);
    z2[t] = a;
  }
  __syncthreads();
  if (t == 0) {
    float mx = z2[0];
    for (int k = 1; k < NCLS; ++k) mx = fmaxf(mx, z2[k]);
    float se = 0.f;
    for (int k = 0; k < NCLS; ++k) se += expf(z2[k] - mx);
    float lse = mx + logf(se);
    for (int k = 0; k < NCLS; ++k) out[b * NCLS + k] = z2[k] - lse;
  }
}

extern "C" void kernel_launch(void* const* d_in, const int* in_sizes, int n_in,
                              void* d_out, int out_size, void* d_ws, size_t ws_size,
                              hipStream_t stream) {
  const float* x   = (const float*)d_in[0];
  const int*  ei   = (const int*)d_in[2];
  const int*  row  = (const int*)d_in[3];
  const int*  col  = (const int*)d_in[4];
  const float* W1  = (const float*)d_in[5];
  const float* b1  = (const float*)d_in[6];
  const float* W2  = (const float*)d_in[7];
  const float* b2  = (const float*)d_in[8];
  const float* W3  = (const float*)d_in[9];
  const float* b3  = (const float*)d_in[10];
  const float* fcw = (const float*)d_in[11];
  const float* fcb = (const float*)d_in[12];
  const float* l1w = (const float*)d_in[13];
  const float* l1b = (const float*)d_in[14];
  const float* l2w = (const float*)d_in[15];
  const float* l2b = (const float*)d_in[16];

  const int BS   = in_sizes[1];               // 8
  const int H    = in_sizes[6];               // 64
  const int F    = in_sizes[5] / H;           // 64
  const int N    = in_sizes[0] / (BS * F);    // 15135
  const int E    = in_sizes[2] / 2;           // 300000
  const int R    = in_sizes[3];               // 40000
  const int HFC  = in_sizes[14];              // 200
  const int NCMT = in_sizes[13] / HFC;        // 400
  const int NCLS = in_sizes[16];              // 2
  const int L    = in_sizes[11] / H;          // 3

  // workspace carve-out (256B aligned)
  char* p = (char*)d_ws;
  auto alloc = [&](size_t bytes) {
    void* r = (void*)p;
    p += (bytes + 255) & ~(size_t)255;
    return r;
  };
  int*   degi      = (int*)alloc((size_t)N * 4);
  int*   cursor    = (int*)alloc((size_t)N * 4);
  int*   row_start = (int*)alloc((size_t)(N + 1) * 4);
  unsigned short* csr = (unsigned short*)alloc((size_t)(E + 8) * 2);  // u16 + pad
  float* dinv      = (float*)alloc((size_t)N * 4);
  float* q         = (float*)alloc((size_t)N * BS * 4);
  float* s_sum     = (float*)alloc((size_t)NCMT * BS * 4);
  float* cntc      = (float*)alloc((size_t)NCMT * 4);
  float* m         = (float*)alloc((size_t)N * BS * H * 4);
  float* hA        = (float*)alloc((size_t)N * BS * H * 4);
  float* hB        = (float*)alloc((size_t)N * BS * H * 4);

  (void)hipMemsetAsync(degi, 0, (size_t)N * 4, stream);
  (void)hipMemsetAsync(cursor, 0, (size_t)N * 4, stream);
  (void)hipMemsetAsync(csr + E, 0, 16, stream);  // zero the pad
  (void)hipMemsetAsync(s_sum, 0, (size_t)NCMT * BS * 4, stream);
  (void)hipMemsetAsync(cntc, 0, (size_t)NCMT * 4, stream);

  const int* e_src = ei;
  const int* e_dst = ei + E;

  count_kernel<<<(E + 255) / 256, 256, 0, stream>>>(e_dst, degi, E);
  prefix_kernel<<<1, 1024, 0, stream>>>(degi, row_start, N);
  fill_kernel<<<(E + 255) / 256, 256, 0, stream>>>(e_src, e_dst, row_start, cursor, csr, E);
  dinv_kernel<<<(N + 255) / 256, 256, 0, stream>>>(degi, dinv, N);

  int lin_grid = ((N + 127) / 128) * BS;  // 2 row-tiles per block
  int agg_grid = ((N + 31) / 32) * BS;    // 8 waves x 4 nodes = 32 nodes/block
  int agg_threads = 512;

  // layer 1 (x is fp32 [b][n][f])
  linear_kernel<<<lin_grid, 256, 0, stream>>>(x, W1, dinv, m, N, BS);
  agg_kernel<true><<<agg_grid, agg_threads, 0, stream>>>(m, dinv, b1, row_start, csr, hA, q, fcw, 0, L, N, BS);
  // layer 2
  linear_kernel<<<lin_grid, 256, 0, stream>>>(hA, W2, dinv, m, N, BS);
  agg_kernel<true><<<agg_grid, agg_threads, 0, stream>>>(m, dinv, b2, row_start, csr, hB, q, fcw, 1, L, N, BS);
  // layer 3 — hout is dead (only q survives), skip the store
  linear_kernel<<<lin_grid, 256, 0, stream>>>(hB, W3, dinv, m, N, BS);
  agg_kernel<false><<<agg_grid, agg_threads, 0, stream>>>(m, dinv, b3, row_start, csr, nullptr, q, fcw, 2, L, N, BS);

  pathway_kernel<<<((size_t)R * BS + 255) / 256, 256, 0, stream>>>(row, col, q, s_sum, cntc, R, N, BS);
  head_kernel<<<BS, 256, 0, stream>>>(s_sum, cntc, fcb, l1w, l1b, l2w, l2b,
                                      (float*)d_out, NCMT, HFC, NCLS, BS);
}

// Round 19
// 363.101 us; speedup vs baseline: 1.1793x; 1.0020x over previous
//
#include <hip/hip_runtime.h>

// ---------------------------------------------------------------------------
// GCNModelWPathways: 3-layer GCN (N nodes, BS=8 batch, H=64) + committee
// pathway pooling + 2-layer MLP head + log_softmax.
//
// Structure: linear (register-tiled, per-slice, unroll-1 loop, 2 row-tiles
// per block) -> agg (pull gather, per-slice, 4-node interleaved waves with
// 1-step csr index prefetch) x3, then pathway + head.
//
// R19: restore index prefetch on the quad-chain agg loop (was in R13 dual,
// dropped in R16 quad). Without it each iteration serializes csr-load ->
// gather (two L2 hops); with it the next step's indices load while this
// step's gathers are in flight. R17 lesson: do NOT issue dead gathers
// (predicated max-loop regressed); prefetched INDEX loads are cheap and
// the pad makes the tail read safe.
//
// Register saga (linear): uncapped=240 VGPR/10% occ; capped w/o shrinking
// live set = spill; unroll-1 + (256,2) = honest fit (R15). NEVER cap below
// the live set. Kept: [R5] b = blockIdx % 8 XCD slice pinning. [R10/R11]
// fp32 features; u16 csr. [R8] csr NEVER nt. [R6] dinv prescale in linear.
// [R12] do NOT fuse agg+linear. [R3] macro params never named x/y/z/w.
// [R9] nt builtins need ext_vector_type.
// ---------------------------------------------------------------------------

using f4v = __attribute__((ext_vector_type(4))) float;

__global__ void count_kernel(const int* __restrict__ dst, int* __restrict__ degi, int E) {
  int e = blockIdx.x * blockDim.x + threadIdx.x;
  if (e < E) atomicAdd(&degi[dst[e]], 1);
}

// single-block exclusive prefix sum over counts[0..n) -> row_start[0..n]
__global__ void prefix_kernel(const int* __restrict__ counts, int* __restrict__ row_start, int n) {
  __shared__ int sums[1024];
  int t = threadIdx.x;
  int chunk = (n + 1023) >> 10;
  int beg = t * chunk;
  int end = min(beg + chunk, n);
  int s = 0;
  for (int i = beg; i < end; ++i) s += counts[i];
  sums[t] = s;
  __syncthreads();
  for (int d = 1; d < 1024; d <<= 1) {
    int v = (t >= d) ? sums[t - d] : 0;
    __syncthreads();
    sums[t] += v;
    __syncthreads();
  }
  int off = (t == 0) ? 0 : sums[t - 1];
  for (int i = beg; i < end; ++i) { row_start[i] = off; off += counts[i]; }
  if (end == n) row_start[n] = off;  // all such threads write the total
}

__global__ void fill_kernel(const int* __restrict__ src, const int* __restrict__ dst,
                            const int* __restrict__ row_start, int* __restrict__ cursor,
                            unsigned short* __restrict__ csr, int E) {
  int e = blockIdx.x * blockDim.x + threadIdx.x;
  if (e < E) {
    int d = dst[e];
    int pos = atomicAdd(&cursor[d], 1);
    csr[row_start[d] + pos] = (unsigned short)src[e];  // N < 65536
  }
}

__global__ void dinv_kernel(const int* __restrict__ degi, float* __restrict__ dinv, int N) {
  int n = blockIdx.x * blockDim.x + threadIdx.x;
  if (n < N) dinv[n] = rsqrtf((float)(degi[n] + 1));  // +1: self-loop
}

// Register-tiled linear on one b-slice:
//   ms[b][r][h] = dinv[r] * sum_f H[b][r][f] * W[h][f]
// Grid = ceil(N/128)*BS; b = blockIdx % BS (XCD-aligned); 256 threads;
// TWO 64-row x 64-h tiles per block (Wt staged once); 4x4 tile per thread
// in named float4 registers. unroll-1 bounds the live set (R15); (256,2).
__global__ __launch_bounds__(256, 2)
void linear_kernel(const float* __restrict__ hin, const float* __restrict__ W,
                   const float* __restrict__ dinv, float* __restrict__ ms,
                   int N, int BS) {
  __shared__ __align__(16) float Xs[64][68];
  __shared__ __align__(16) float Wt[64][68];  // Wt[f][h]
  int t = threadIdx.x;
  int b = blockIdx.x % BS;
  int chunk = blockIdx.x / BS;
  size_t bN64 = (size_t)b * N * 64;

  // stage W transposed once per block
  for (int i = t; i < 4096; i += 256) {
    int h = i >> 6, f = i & 63;
    Wt[f][h] = W[i];
  }

  int hg = t & 15;   // h0 = 4*hg
  int rg = t >> 4;   // r0 = 4*rg
  int r0 = 4 * rg;
  int xr_row = t >> 2;   // X-stage: 4 threads per row
  int xr_c0 = t & 3;

// NOTE: macro params must NOT be named x/y/z/w (round-3 compile failure).
#define FMA4(A, S, V)            \
  A.x = fmaf((S), (V).x, A.x);   \
  A.y = fmaf((S), (V).y, A.y);   \
  A.z = fmaf((S), (V).z, A.z);   \
  A.w = fmaf((S), (V).w, A.w);

#pragma unroll 1
  for (int tile = 0; tile < 2; ++tile) {
    int row0 = chunk * 128 + tile * 64;
    if (row0 >= N) break;
    int nrows = min(64, N - row0);
    size_t sbase = bN64 + (size_t)row0 * 64;

    __syncthreads();  // Wt ready (tile 0) / previous-tile reads done (tile 1)
    // stage X tile
    {
      bool valid = xr_row < nrows;
      const float* srcp = hin + sbase + (size_t)xr_row * 64;
#pragma unroll
      for (int c = 0; c < 4; ++c) {
        int f4 = xr_c0 + c * 4;
        float4 v = valid ? reinterpret_cast<const float4*>(srcp)[f4]
                         : float4{0.f, 0.f, 0.f, 0.f};
        *reinterpret_cast<float4*>(&Xs[xr_row][4 * f4]) = v;
      }
    }
    __syncthreads();

    float4 acc0 = {0.f, 0.f, 0.f, 0.f};
    float4 acc1 = {0.f, 0.f, 0.f, 0.f};
    float4 acc2 = {0.f, 0.f, 0.f, 0.f};
    float4 acc3 = {0.f, 0.f, 0.f, 0.f};

#pragma unroll 1  // bound the live set: one iteration's staging (8 f4) only
    for (int i = 0; i < 16; ++i) {  // f0 = 4*i
      float4 xr0 = *reinterpret_cast<const float4*>(&Xs[r0 + 0][4 * i]);
      float4 xr1 = *reinterpret_cast<const float4*>(&Xs[r0 + 1][4 * i]);
      float4 xr2 = *reinterpret_cast<const float4*>(&Xs[r0 + 2][4 * i]);
      float4 xr3 = *reinterpret_cast<const float4*>(&Xs[r0 + 3][4 * i]);
      float4 wv0 = *reinterpret_cast<const float4*>(&Wt[4 * i + 0][4 * hg]);
      float4 wv1 = *reinterpret_cast<const float4*>(&Wt[4 * i + 1][4 * hg]);
      float4 wv2 = *reinterpret_cast<const float4*>(&Wt[4 * i + 2][4 * hg]);
      float4 wv3 = *reinterpret_cast<const float4*>(&Wt[4 * i + 3][4 * hg]);
      FMA4(acc0, xr0.x, wv0); FMA4(acc0, xr0.y, wv1); FMA4(acc0, xr0.z, wv2); FMA4(acc0, xr0.w, wv3);
      FMA4(acc1, xr1.x, wv0); FMA4(acc1, xr1.y, wv1); FMA4(acc1, xr1.z, wv2); FMA4(acc1, xr1.w, wv3);
      FMA4(acc2, xr2.x, wv0); FMA4(acc2, xr2.y, wv1); FMA4(acc2, xr2.z, wv2); FMA4(acc2, xr2.w, wv3);
      FMA4(acc3, xr3.x, wv0); FMA4(acc3, xr3.y, wv1); FMA4(acc3, xr3.z, wv2); FMA4(acc3, xr3.w, wv3);
    }

    // epilogue: scale by dinv[row] (pre-scaled gather operand), float4 store
#define STORE_S(A, RIDX)                                                   \
    if ((RIDX) < nrows) {                                                  \
      float d = dinv[row0 + (RIDX)];                                       \
      float4 o = {A.x * d, A.y * d, A.z * d, A.w * d};                     \
      reinterpret_cast<float4*>(&ms[sbase + (size_t)(RIDX) * 64])[hg] = o; \
    }
    STORE_S(acc0, r0 + 0)
    STORE_S(acc1, r0 + 1)
    STORE_S(acc2, r0 + 2)
    STORE_S(acc3, r0 + 3)
#undef STORE_S
  }
#undef FMA4
}

// Pull aggregation on one b-slice. Grid = ceil(N/32)*BS; b = blockIdx % BS.
// Block = 512 threads = 8 waves; each wave owns FOUR nodes with interleaved
// gather chains (R16) and 1-step csr index prefetch (R19): next step's 4
// indices load while this step's 4 gathers are in flight — removes the
// csr->gather two-hop serialization. csr pad (8 zeroed u16) makes the tail
// prefetch safe. eg = lane>>4 (edge slot), hq = lane&15 (h quad).
template <bool WRITE_H>
__global__ void agg_kernel(const float* __restrict__ ms, const float* __restrict__ dinv,
                           const float* __restrict__ bias, const int* __restrict__ row_start,
                           const unsigned short* __restrict__ csr, float* __restrict__ hout,
                           float* __restrict__ q, const float* __restrict__ fcw,
                           int layer, int L, int N, int BS) {
  int b = blockIdx.x % BS;
  int chunk = blockIdx.x / BS;
  int wv = threadIdx.x >> 6, lane = threadIdx.x & 63;
  int nA = chunk * 32 + 4 * wv;
  if (nA >= N) return;
  int nB = nA + 1, nC = nA + 2, nD = nA + 3;
  bool okB = nB < N, okC = nC < N, okD = nD < N;
  int eg = lane >> 4;     // edge slot 0..3
  int hq = lane & 15;     // h quad: h = 4*hq .. 4*hq+3
  size_t bN = (size_t)b * N;
  const float* mb = ms + bN * 64;

  f4v accA = {0.f, 0.f, 0.f, 0.f};
  f4v accB = {0.f, 0.f, 0.f, 0.f};
  f4v accC = {0.f, 0.f, 0.f, 0.f};
  f4v accD = {0.f, 0.f, 0.f, 0.f};
  // self-loops (counted once — eg 0 only)
  if (eg == 0) {
    accA = *reinterpret_cast<const f4v*>(mb + (size_t)nA * 64 + 4 * hq);
    if (okB) accB = *reinterpret_cast<const f4v*>(mb + (size_t)nB * 64 + 4 * hq);
    if (okC) accC = *reinterpret_cast<const f4v*>(mb + (size_t)nC * 64 + 4 * hq);
    if (okD) accD = *reinterpret_cast<const f4v*>(mb + (size_t)nD * 64 + 4 * hq);
  }

  int begA = row_start[nA], endA = row_start[nA + 1];
  int begB = begA, endB = begA, begC = begA, endC = begA, begD = begA, endD = begA;
  if (okB) { begB = row_start[nB]; endB = row_start[nB + 1]; }
  if (okC) { begC = row_start[nC]; endC = row_start[nC + 1]; }
  if (okD) { begD = row_start[nD]; endD = row_start[nD + 1]; }
  int ia = begA, ib = begB, ic = begC, id = begD;
  int mA = begA + ((endA - begA) & ~3);
  int mB = begB + ((endB - begB) & ~3);
  int mC = begC + ((endC - begC) & ~3);
  int mD = begD + ((endD - begD) & ~3);

  // quad interleaved main loop with 1-step index prefetch:
  // step s's 4 gathers issue from registered indices while step s+1's
  // 4 index loads proceed in parallel (pad covers the tail read).
  if (ia < mA && ib < mB && ic < mC && id < mD) {
    int sa = csr[ia + eg];
    int sb = csr[ib + eg];
    int sc = csr[ic + eg];
    int sd = csr[id + eg];
    while (true) {
      int sa_n = csr[ia + 4 + eg];   // may read zeroed pad — unused then
      int sb_n = csr[ib + 4 + eg];
      int sc_n = csr[ic + 4 + eg];
      int sd_n = csr[id + 4 + eg];
      f4v va = *reinterpret_cast<const f4v*>(mb + (size_t)sa * 64 + 4 * hq);
      f4v vb = *reinterpret_cast<const f4v*>(mb + (size_t)sb * 64 + 4 * hq);
      f4v vc = *reinterpret_cast<const f4v*>(mb + (size_t)sc * 64 + 4 * hq);
      f4v vd = *reinterpret_cast<const f4v*>(mb + (size_t)sd * 64 + 4 * hq);
      accA += va; accB += vb; accC += vc; accD += vd;
      ia += 4; ib += 4; ic += 4; id += 4;
      if (ia >= mA || ib >= mB || ic >= mC || id >= mD) break;
      sa = sa_n; sb = sb_n; sc = sc_n; sd = sd_n;
    }
  }
  // drain remaining full steps per chain
#define DRAIN(ACC, I, M)                                                     \
  while ((I) < (M)) {                                                        \
    int s_ = csr[(I) + eg];                                                  \
    (ACC) += *reinterpret_cast<const f4v*>(mb + (size_t)s_ * 64 + 4 * hq);   \
    (I) += 4;                                                                \
  }
  DRAIN(accA, ia, mA)
  DRAIN(accB, ib, mB)
  DRAIN(accC, ic, mC)
  DRAIN(accD, id, mD)
#undef DRAIN
  // remainders (0..3 edges each)
#define REMD(ACC, I, END)                                                    \
  {                                                                          \
    int rem_ = (END) - (I);                                                  \
    if (rem_ > 0) {                                                          \
      int e_ = (I) + ((eg < rem_) ? eg : 0);                                 \
      int s_ = csr[e_];                                                      \
      f4v v_ = *reinterpret_cast<const f4v*>(mb + (size_t)s_ * 64 + 4 * hq); \
      if (eg < rem_) (ACC) += v_;                                            \
    }                                                                        \
  }
  REMD(accA, ia, endA)
  REMD(accB, ib, endB)
  REMD(accC, ic, endC)
  REMD(accD, id, endD)
#undef REMD

  // reduce across the 4 edge-slot groups (lanes differing in bits 4,5)
#define RED(ACC)                                              \
  (ACC).x += __shfl_xor((ACC).x, 16); (ACC).y += __shfl_xor((ACC).y, 16);  \
  (ACC).z += __shfl_xor((ACC).z, 16); (ACC).w += __shfl_xor((ACC).w, 16);  \
  (ACC).x += __shfl_xor((ACC).x, 32); (ACC).y += __shfl_xor((ACC).y, 32);  \
  (ACC).z += __shfl_xor((ACC).z, 32); (ACC).w += __shfl_xor((ACC).w, 32);
  RED(accA) RED(accB) RED(accC) RED(accD)
#undef RED

  float4 bias4 = *reinterpret_cast<const float4*>(&bias[4 * hq]);
  int h0 = 4 * hq;
  float fw0 = fcw[(h0 + 0) * L + layer];
  float fw1 = fcw[(h0 + 1) * L + layer];
  float fw2 = fcw[(h0 + 2) * L + layer];
  float fw3 = fcw[(h0 + 3) * L + layer];

#define FINISH(ACC, NODE, OK)                                                  \
  {                                                                            \
    float dn_ = (OK) ? dinv[NODE] : 0.f;                                       \
    f4v val_;                                                                  \
    val_.x = fmaxf(fmaf(dn_, (ACC).x, bias4.x), 0.f);                          \
    val_.y = fmaxf(fmaf(dn_, (ACC).y, bias4.y), 0.f);                          \
    val_.z = fmaxf(fmaf(dn_, (ACC).z, bias4.z), 0.f);                          \
    val_.w = fmaxf(fmaf(dn_, (ACC).w, bias4.w), 0.f);                          \
    if (WRITE_H && eg == 0 && (OK))                                            \
      __builtin_nontemporal_store(val_,                                        \
          reinterpret_cast<f4v*>(hout + bN * 64 + (size_t)(NODE) * 64 + 4 * hq)); \
    float qp_ = val_.x * fw0 + val_.y * fw1 + val_.z * fw2 + val_.w * fw3;     \
    qp_ += __shfl_xor(qp_, 1); qp_ += __shfl_xor(qp_, 2);                      \
    qp_ += __shfl_xor(qp_, 4); qp_ += __shfl_xor(qp_, 8);                      \
    if (lane == 0 && (OK)) {                                                   \
      if (layer == 0) q[bN + (NODE)] = qp_;                                    \
      else q[bN + (NODE)] += qp_;                                              \
    }                                                                          \
  }
  FINISH(accA, nA, true)
  FINISH(accB, nB, okB)
  FINISH(accC, nC, okC)
  FINISH(accD, nD, okD)
#undef FINISH
}

__global__ void pathway_kernel(const int* __restrict__ row, const int* __restrict__ col,
                               const float* __restrict__ q, float* __restrict__ s_sum,
                               float* __restrict__ cntc, int R, int N, int BS) {
  int idx = blockIdx.x * blockDim.x + threadIdx.x;
  if (idx >= R * BS) return;
  int r = idx / BS, b = idx - (idx / BS) * BS;
  int c = col[r], nd = row[r];
  atomicAdd(&s_sum[c * BS + b], q[(size_t)b * N + nd]);
  if (b == 0) atomicAdd(&cntc[c], 1.0f);
}

__global__ void head_kernel(const float* __restrict__ s_sum, const float* __restrict__ cntc,
                            const float* __restrict__ fcb, const float* __restrict__ l1w,
                            const float* __restrict__ l1b, const float* __restrict__ l2w,
                            const float* __restrict__ l2b, float* __restrict__ out,
                            int NCMT, int HFC, int NCLS, int BS) {
  int b = blockIdx.x;
  __shared__ float sbuf[400];
  __shared__ float z1[200];
  __shared__ float z2[8];
  int t = threadIdx.x;  // 256
  for (int c = t; c < NCMT; c += 256) {
    float cn = fmaxf(cntc[c], 1.0f);
    sbuf[c] = s_sum[c * BS + b] / cn + fcb[0];
  }
  __syncthreads();
  for (int j = t; j < HFC; j += 256) {
    float a = l1b[j];
    for (int c = 0; c < NCMT; ++c) a = fmaf(sbuf[c], l1w[j * NCMT + c], a);
    z1[j] = fmaxf(a, 0.f);
  }
  __syncthreads();
  if (t < NCLS) {
    float a = l2b[t];
    for (int j = 0; j < HFC; ++j) a = fmaf(z1[j], l2w[t * HFC + j], a);
    z2[t] = a;
  }
  __syncthreads();
  if (t == 0) {
    float mx = z2[0];
    for (int k = 1; k < NCLS; ++k) mx = fmaxf(mx, z2[k]);
    float se = 0.f;
    for (int k = 0; k < NCLS; ++k) se += expf(z2[k] - mx);
    float lse = mx + logf(se);
    for (int k = 0; k < NCLS; ++k) out[b * NCLS + k] = z2[k] - lse;
  }
}

extern "C" void kernel_launch(void* const* d_in, const int* in_sizes, int n_in,
                              void* d_out, int out_size, void* d_ws, size_t ws_size,
                              hipStream_t stream) {
  const float* x   = (const float*)d_in[0];
  const int*  ei   = (const int*)d_in[2];
  const int*  row  = (const int*)d_in[3];
  const int*  col  = (const int*)d_in[4];
  const float* W1  = (const float*)d_in[5];
  const float* b1  = (const float*)d_in[6];
  const float* W2  = (const float*)d_in[7];
  const float* b2  = (const float*)d_in[8];
  const float* W3  = (const float*)d_in[9];
  const float* b3  = (const float*)d_in[10];
  const float* fcw = (const float*)d_in[11];
  const float* fcb = (const float*)d_in[12];
  const float* l1w = (const float*)d_in[13];
  const float* l1b = (const float*)d_in[14];
  const float* l2w = (const float*)d_in[15];
  const float* l2b = (const float*)d_in[16];

  const int BS   = in_sizes[1];               // 8
  const int H    = in_sizes[6];               // 64
  const int F    = in_sizes[5] / H;           // 64
  const int N    = in_sizes[0] / (BS * F);    // 15135
  const int E    = in_sizes[2] / 2;           // 300000
  const int R    = in_sizes[3];               // 40000
  const int HFC  = in_sizes[14];              // 200
  const int NCMT = in_sizes[13] / HFC;        // 400
  const int NCLS = in_sizes[16];              // 2
  const int L    = in_sizes[11] / H;          // 3

  // workspace carve-out (256B aligned)
  char* p = (char*)d_ws;
  auto alloc = [&](size_t bytes) {
    void* r = (void*)p;
    p += (bytes + 255) & ~(size_t)255;
    return r;
  };
  int*   degi      = (int*)alloc((size_t)N * 4);
  int*   cursor    = (int*)alloc((size_t)N * 4);
  int*   row_start = (int*)alloc((size_t)(N + 1) * 4);
  unsigned short* csr = (unsigned short*)alloc((size_t)(E + 8) * 2);  // u16 + pad
  float* dinv      = (float*)alloc((size_t)N * 4);
  float* q         = (float*)alloc((size_t)N * BS * 4);
  float* s_sum     = (float*)alloc((size_t)NCMT * BS * 4);
  float* cntc      = (float*)alloc((size_t)NCMT * 4);
  float* m         = (float*)alloc((size_t)N * BS * H * 4);
  float* hA        = (float*)alloc((size_t)N * BS * H * 4);
  float* hB        = (float*)alloc((size_t)N * BS * H * 4);

  (void)hipMemsetAsync(degi, 0, (size_t)N * 4, stream);
  (void)hipMemsetAsync(cursor, 0, (size_t)N * 4, stream);
  (void)hipMemsetAsync(csr + E, 0, 16, stream);  // zero the pad
  (void)hipMemsetAsync(s_sum, 0, (size_t)NCMT * BS * 4, stream);
  (void)hipMemsetAsync(cntc, 0, (size_t)NCMT * 4, stream);

  const int* e_src = ei;
  const int* e_dst = ei + E;

  count_kernel<<<(E + 255) / 256, 256, 0, stream>>>(e_dst, degi, E);
  prefix_kernel<<<1, 1024, 0, stream>>>(degi, row_start, N);
  fill_kernel<<<(E + 255) / 256, 256, 0, stream>>>(e_src, e_dst, row_start, cursor, csr, E);
  dinv_kernel<<<(N + 255) / 256, 256, 0, stream>>>(degi, dinv, N);

  int lin_grid = ((N + 127) / 128) * BS;  // 2 row-tiles per block
  int agg_grid = ((N + 31) / 32) * BS;    // 8 waves x 4 nodes = 32 nodes/block
  int agg_threads = 512;

  // layer 1 (x is fp32 [b][n][f])
  linear_kernel<<<lin_grid, 256, 0, stream>>>(x, W1, dinv, m, N, BS);
  agg_kernel<true><<<agg_grid, agg_threads, 0, stream>>>(m, dinv, b1, row_start, csr, hA, q, fcw, 0, L, N, BS);
  // layer 2
  linear_kernel<<<lin_grid, 256, 0, stream>>>(hA, W2, dinv, m, N, BS);
  agg_kernel<true><<<agg_grid, agg_threads, 0, stream>>>(m, dinv, b2, row_start, csr, hB, q, fcw, 1, L, N, BS);
  // layer 3 — hout is dead (only q survives), skip the store
  linear_kernel<<<lin_grid, 256, 0, stream>>>(hB, W3, dinv, m, N, BS);
  agg_kernel<false><<<agg_grid, agg_threads, 0, stream>>>(m, dinv, b3, row_start, csr, nullptr, q, fcw, 2, L, N, BS);

  pathway_kernel<<<((size_t)R * BS + 255) / 256, 256, 0, stream>>>(row, col, q, s_sum, cntc, R, N, BS);
  head_kernel<<<BS, 256, 0, stream>>>(s_sum, cntc, fcb, l1w, l1b, l2w, l2b,
                                      (float*)d_out, NCMT, HFC, NCLS, BS);
}

// Round 20
// 344.166 us; speedup vs baseline: 1.2442x; 1.0550x over previous
//
#include <hip/hip_runtime.h>

// ---------------------------------------------------------------------------
// GCNModelWPathways: 3-layer GCN (N nodes, BS=8 batch, H=64) + committee
// pathway pooling + 2-layer MLP head + log_softmax.
//
// Structure: linear (register-tiled, per-slice, unroll-1 loop, 2 row-tiles
// per block) -> agg (pull gather, per-slice, 4-node interleaved waves) x3,
// then pathway + head.
//
// R20: agg blocks 512 -> 256 threads (+launch_bounds(256,8)). agg is
// loaded-latency bound: in-flight bytes/CU = 4x256B x resident waves; at
// 61% occupancy that's ~20KB < ~34KB needed. 256-thread blocks halve the
// residency quantum (4 waves vs 8) -> better packing; bounds request the
// 8-waves/SIMD tier (VGPR 32 fits easily). Memsets merged 4 -> 2.
// R19 lesson: csr index prefetch was NULL (indices already L1-hot, 64/line).
// R17 lesson: predicated dead gathers REGRESS. R16: >4 chains/wave saturates.
//
// Register saga (linear): uncapped=240 VGPR/10% occ; capped w/o shrinking
// live set = spill; unroll-1 + (256,2) = honest fit (R15). NEVER cap below
// the live set. Kept: [R5] b = blockIdx % 8 XCD slice pinning. [R10/R11]
// fp32 features; u16 csr. [R8] csr NEVER nt. [R6] dinv prescale in linear.
// [R12] do NOT fuse agg+linear. [R3] macro params never named x/y/z/w.
// [R9] nt builtins need ext_vector_type.
// ---------------------------------------------------------------------------

using f4v = __attribute__((ext_vector_type(4))) float;

__global__ void count_kernel(const int* __restrict__ dst, int* __restrict__ degi, int E) {
  int e = blockIdx.x * blockDim.x + threadIdx.x;
  if (e < E) atomicAdd(&degi[dst[e]], 1);
}

// single-block exclusive prefix sum over counts[0..n) -> row_start[0..n]
__global__ void prefix_kernel(const int* __restrict__ counts, int* __restrict__ row_start, int n) {
  __shared__ int sums[1024];
  int t = threadIdx.x;
  int chunk = (n + 1023) >> 10;
  int beg = t * chunk;
  int end = min(beg + chunk, n);
  int s = 0;
  for (int i = beg; i < end; ++i) s += counts[i];
  sums[t] = s;
  __syncthreads();
  for (int d = 1; d < 1024; d <<= 1) {
    int v = (t >= d) ? sums[t - d] : 0;
    __syncthreads();
    sums[t] += v;
    __syncthreads();
  }
  int off = (t == 0) ? 0 : sums[t - 1];
  for (int i = beg; i < end; ++i) { row_start[i] = off; off += counts[i]; }
  if (end == n) row_start[n] = off;  // all such threads write the total
}

__global__ void fill_kernel(const int* __restrict__ src, const int* __restrict__ dst,
                            const int* __restrict__ row_start, int* __restrict__ cursor,
                            unsigned short* __restrict__ csr, int E) {
  int e = blockIdx.x * blockDim.x + threadIdx.x;
  if (e < E) {
    int d = dst[e];
    int pos = atomicAdd(&cursor[d], 1);
    csr[row_start[d] + pos] = (unsigned short)src[e];  // N < 65536
  }
}

__global__ void dinv_kernel(const int* __restrict__ degi, float* __restrict__ dinv, int N) {
  int n = blockIdx.x * blockDim.x + threadIdx.x;
  if (n < N) dinv[n] = rsqrtf((float)(degi[n] + 1));  // +1: self-loop
}

// Register-tiled linear on one b-slice:
//   ms[b][r][h] = dinv[r] * sum_f H[b][r][f] * W[h][f]
// Grid = ceil(N/128)*BS; b = blockIdx % BS (XCD-aligned); 256 threads;
// TWO 64-row x 64-h tiles per block (Wt staged once); 4x4 tile per thread
// in named float4 registers. unroll-1 bounds the live set (R15); (256,2).
__global__ __launch_bounds__(256, 2)
void linear_kernel(const float* __restrict__ hin, const float* __restrict__ W,
                   const float* __restrict__ dinv, float* __restrict__ ms,
                   int N, int BS) {
  __shared__ __align__(16) float Xs[64][68];
  __shared__ __align__(16) float Wt[64][68];  // Wt[f][h]
  int t = threadIdx.x;
  int b = blockIdx.x % BS;
  int chunk = blockIdx.x / BS;
  size_t bN64 = (size_t)b * N * 64;

  // stage W transposed once per block
  for (int i = t; i < 4096; i += 256) {
    int h = i >> 6, f = i & 63;
    Wt[f][h] = W[i];
  }

  int hg = t & 15;   // h0 = 4*hg
  int rg = t >> 4;   // r0 = 4*rg
  int r0 = 4 * rg;
  int xr_row = t >> 2;   // X-stage: 4 threads per row
  int xr_c0 = t & 3;

// NOTE: macro params must NOT be named x/y/z/w (round-3 compile failure).
#define FMA4(A, S, V)            \
  A.x = fmaf((S), (V).x, A.x);   \
  A.y = fmaf((S), (V).y, A.y);   \
  A.z = fmaf((S), (V).z, A.z);   \
  A.w = fmaf((S), (V).w, A.w);

#pragma unroll 1
  for (int tile = 0; tile < 2; ++tile) {
    int row0 = chunk * 128 + tile * 64;
    if (row0 >= N) break;
    int nrows = min(64, N - row0);
    size_t sbase = bN64 + (size_t)row0 * 64;

    __syncthreads();  // Wt ready (tile 0) / previous-tile reads done (tile 1)
    // stage X tile
    {
      bool valid = xr_row < nrows;
      const float* srcp = hin + sbase + (size_t)xr_row * 64;
#pragma unroll
      for (int c = 0; c < 4; ++c) {
        int f4 = xr_c0 + c * 4;
        float4 v = valid ? reinterpret_cast<const float4*>(srcp)[f4]
                         : float4{0.f, 0.f, 0.f, 0.f};
        *reinterpret_cast<float4*>(&Xs[xr_row][4 * f4]) = v;
      }
    }
    __syncthreads();

    float4 acc0 = {0.f, 0.f, 0.f, 0.f};
    float4 acc1 = {0.f, 0.f, 0.f, 0.f};
    float4 acc2 = {0.f, 0.f, 0.f, 0.f};
    float4 acc3 = {0.f, 0.f, 0.f, 0.f};

#pragma unroll 1  // bound the live set: one iteration's staging (8 f4) only
    for (int i = 0; i < 16; ++i) {  // f0 = 4*i
      float4 xr0 = *reinterpret_cast<const float4*>(&Xs[r0 + 0][4 * i]);
      float4 xr1 = *reinterpret_cast<const float4*>(&Xs[r0 + 1][4 * i]);
      float4 xr2 = *reinterpret_cast<const float4*>(&Xs[r0 + 2][4 * i]);
      float4 xr3 = *reinterpret_cast<const float4*>(&Xs[r0 + 3][4 * i]);
      float4 wv0 = *reinterpret_cast<const float4*>(&Wt[4 * i + 0][4 * hg]);
      float4 wv1 = *reinterpret_cast<const float4*>(&Wt[4 * i + 1][4 * hg]);
      float4 wv2 = *reinterpret_cast<const float4*>(&Wt[4 * i + 2][4 * hg]);
      float4 wv3 = *reinterpret_cast<const float4*>(&Wt[4 * i + 3][4 * hg]);
      FMA4(acc0, xr0.x, wv0); FMA4(acc0, xr0.y, wv1); FMA4(acc0, xr0.z, wv2); FMA4(acc0, xr0.w, wv3);
      FMA4(acc1, xr1.x, wv0); FMA4(acc1, xr1.y, wv1); FMA4(acc1, xr1.z, wv2); FMA4(acc1, xr1.w, wv3);
      FMA4(acc2, xr2.x, wv0); FMA4(acc2, xr2.y, wv1); FMA4(acc2, xr2.z, wv2); FMA4(acc2, xr2.w, wv3);
      FMA4(acc3, xr3.x, wv0); FMA4(acc3, xr3.y, wv1); FMA4(acc3, xr3.z, wv2); FMA4(acc3, xr3.w, wv3);
    }

    // epilogue: scale by dinv[row] (pre-scaled gather operand), float4 store
#define STORE_S(A, RIDX)                                                   \
    if ((RIDX) < nrows) {                                                  \
      float d = dinv[row0 + (RIDX)];                                       \
      float4 o = {A.x * d, A.y * d, A.z * d, A.w * d};                     \
      reinterpret_cast<float4*>(&ms[sbase + (size_t)(RIDX) * 64])[hg] = o; \
    }
    STORE_S(acc0, r0 + 0)
    STORE_S(acc1, r0 + 1)
    STORE_S(acc2, r0 + 2)
    STORE_S(acc3, r0 + 3)
#undef STORE_S
  }
#undef FMA4
}

// Pull aggregation on one b-slice. Grid = ceil(N/16)*BS; b = blockIdx % BS.
// Block = 256 threads = 4 waves (R20: halves the residency quantum vs 512,
// launch_bounds requests the full 8-waves/SIMD tier); each wave owns FOUR
// nodes with interleaved gather chains (R16). eg = lane>>4 (edge slot 0..3),
// hq = lane&15 (h quad). u16 csr (L2-cached, NOT nt). fp32 accumulate.
template <bool WRITE_H>
__global__ __launch_bounds__(256, 8)
void agg_kernel(const float* __restrict__ ms, const float* __restrict__ dinv,
                const float* __restrict__ bias, const int* __restrict__ row_start,
                const unsigned short* __restrict__ csr, float* __restrict__ hout,
                float* __restrict__ q, const float* __restrict__ fcw,
                int layer, int L, int N, int BS) {
  int b = blockIdx.x % BS;
  int chunk = blockIdx.x / BS;
  int wv = threadIdx.x >> 6, lane = threadIdx.x & 63;
  int nA = chunk * 16 + 4 * wv;
  if (nA >= N) return;
  int nB = nA + 1, nC = nA + 2, nD = nA + 3;
  bool okB = nB < N, okC = nC < N, okD = nD < N;
  int eg = lane >> 4;     // edge slot 0..3
  int hq = lane & 15;     // h quad: h = 4*hq .. 4*hq+3
  size_t bN = (size_t)b * N;
  const float* mb = ms + bN * 64;

  f4v accA = {0.f, 0.f, 0.f, 0.f};
  f4v accB = {0.f, 0.f, 0.f, 0.f};
  f4v accC = {0.f, 0.f, 0.f, 0.f};
  f4v accD = {0.f, 0.f, 0.f, 0.f};
  // self-loops (counted once — eg 0 only)
  if (eg == 0) {
    accA = *reinterpret_cast<const f4v*>(mb + (size_t)nA * 64 + 4 * hq);
    if (okB) accB = *reinterpret_cast<const f4v*>(mb + (size_t)nB * 64 + 4 * hq);
    if (okC) accC = *reinterpret_cast<const f4v*>(mb + (size_t)nC * 64 + 4 * hq);
    if (okD) accD = *reinterpret_cast<const f4v*>(mb + (size_t)nD * 64 + 4 * hq);
  }

  int begA = row_start[nA], endA = row_start[nA + 1];
  int begB = begA, endB = begA, begC = begA, endC = begA, begD = begA, endD = begA;
  if (okB) { begB = row_start[nB]; endB = row_start[nB + 1]; }
  if (okC) { begC = row_start[nC]; endC = row_start[nC + 1]; }
  if (okD) { begD = row_start[nD]; endD = row_start[nD + 1]; }
  int ia = begA, ib = begB, ic = begC, id = begD;
  int mA = begA + ((endA - begA) & ~3);
  int mB = begB + ((endB - begB) & ~3);
  int mC = begC + ((endC - begC) & ~3);
  int mD = begD + ((endD - begD) & ~3);

  // quad interleaved main loop: 4 independent gather chains in flight
  while (ia < mA && ib < mB && ic < mC && id < mD) {
    int sa = csr[ia + eg];
    int sb = csr[ib + eg];
    int sc = csr[ic + eg];
    int sd = csr[id + eg];
    f4v va = *reinterpret_cast<const f4v*>(mb + (size_t)sa * 64 + 4 * hq);
    f4v vb = *reinterpret_cast<const f4v*>(mb + (size_t)sb * 64 + 4 * hq);
    f4v vc = *reinterpret_cast<const f4v*>(mb + (size_t)sc * 64 + 4 * hq);
    f4v vd = *reinterpret_cast<const f4v*>(mb + (size_t)sd * 64 + 4 * hq);
    accA += va; accB += vb; accC += vc; accD += vd;
    ia += 4; ib += 4; ic += 4; id += 4;
  }
  // drain remaining full steps per chain
#define DRAIN(ACC, I, M)                                                     \
  while ((I) < (M)) {                                                        \
    int s_ = csr[(I) + eg];                                                  \
    (ACC) += *reinterpret_cast<const f4v*>(mb + (size_t)s_ * 64 + 4 * hq);   \
    (I) += 4;                                                                \
  }
  DRAIN(accA, ia, mA)
  DRAIN(accB, ib, mB)
  DRAIN(accC, ic, mC)
  DRAIN(accD, id, mD)
#undef DRAIN
  // remainders (0..3 edges each)
#define REMD(ACC, I, END)                                                    \
  {                                                                          \
    int rem_ = (END) - (I);                                                  \
    if (rem_ > 0) {                                                          \
      int e_ = (I) + ((eg < rem_) ? eg : 0);                                 \
      int s_ = csr[e_];                                                      \
      f4v v_ = *reinterpret_cast<const f4v*>(mb + (size_t)s_ * 64 + 4 * hq); \
      if (eg < rem_) (ACC) += v_;                                            \
    }                                                                        \
  }
  REMD(accA, ia, endA)
  REMD(accB, ib, endB)
  REMD(accC, ic, endC)
  REMD(accD, id, endD)
#undef REMD

  // reduce across the 4 edge-slot groups (lanes differing in bits 4,5)
#define RED(ACC)                                              \
  (ACC).x += __shfl_xor((ACC).x, 16); (ACC).y += __shfl_xor((ACC).y, 16);  \
  (ACC).z += __shfl_xor((ACC).z, 16); (ACC).w += __shfl_xor((ACC).w, 16);  \
  (ACC).x += __shfl_xor((ACC).x, 32); (ACC).y += __shfl_xor((ACC).y, 32);  \
  (ACC).z += __shfl_xor((ACC).z, 32); (ACC).w += __shfl_xor((ACC).w, 32);
  RED(accA) RED(accB) RED(accC) RED(accD)
#undef RED

  float4 bias4 = *reinterpret_cast<const float4*>(&bias[4 * hq]);
  int h0 = 4 * hq;
  float fw0 = fcw[(h0 + 0) * L + layer];
  float fw1 = fcw[(h0 + 1) * L + layer];
  float fw2 = fcw[(h0 + 2) * L + layer];
  float fw3 = fcw[(h0 + 3) * L + layer];

#define FINISH(ACC, NODE, OK)                                                  \
  {                                                                            \
    float dn_ = (OK) ? dinv[NODE] : 0.f;                                       \
    f4v val_;                                                                  \
    val_.x = fmaxf(fmaf(dn_, (ACC).x, bias4.x), 0.f);                          \
    val_.y = fmaxf(fmaf(dn_, (ACC).y, bias4.y), 0.f);                          \
    val_.z = fmaxf(fmaf(dn_, (ACC).z, bias4.z), 0.f);                          \
    val_.w = fmaxf(fmaf(dn_, (ACC).w, bias4.w), 0.f);                          \
    if (WRITE_H && eg == 0 && (OK))                                            \
      __builtin_nontemporal_store(val_,                                        \
          reinterpret_cast<f4v*>(hout + bN * 64 + (size_t)(NODE) * 64 + 4 * hq)); \
    float qp_ = val_.x * fw0 + val_.y * fw1 + val_.z * fw2 + val_.w * fw3;     \
    qp_ += __shfl_xor(qp_, 1); qp_ += __shfl_xor(qp_, 2);                      \
    qp_ += __shfl_xor(qp_, 4); qp_ += __shfl_xor(qp_, 8);                      \
    if (lane == 0 && (OK)) {                                                   \
      if (layer == 0) q[bN + (NODE)] = qp_;                                    \
      else q[bN + (NODE)] += qp_;                                              \
    }                                                                          \
  }
  FINISH(accA, nA, true)
  FINISH(accB, nB, okB)
  FINISH(accC, nC, okC)
  FINISH(accD, nD, okD)
#undef FINISH
}

__global__ void pathway_kernel(const int* __restrict__ row, const int* __restrict__ col,
                               const float* __restrict__ q, float* __restrict__ s_sum,
                               float* __restrict__ cntc, int R, int N, int BS) {
  int idx = blockIdx.x * blockDim.x + threadIdx.x;
  if (idx >= R * BS) return;
  int r = idx / BS, b = idx - (idx / BS) * BS;
  int c = col[r], nd = row[r];
  atomicAdd(&s_sum[c * BS + b], q[(size_t)b * N + nd]);
  if (b == 0) atomicAdd(&cntc[c], 1.0f);
}

__global__ void head_kernel(const float* __restrict__ s_sum, const float* __restrict__ cntc,
                            const float* __restrict__ fcb, const float* __restrict__ l1w,
                            const float* __restrict__ l1b, const float* __restrict__ l2w,
                            const float* __restrict__ l2b, float* __restrict__ out,
                            int NCMT, int HFC, int NCLS, int BS) {
  int b = blockIdx.x;
  __shared__ float sbuf[400];
  __shared__ float z1[200];
  __shared__ float z2[8];
  int t = threadIdx.x;  // 256
  for (int c = t; c < NCMT; c += 256) {
    float cn = fmaxf(cntc[c], 1.0f);
    sbuf[c] = s_sum[c * BS + b] / cn + fcb[0];
  }
  __syncthreads();
  for (int j = t; j < HFC; j += 256) {
    float a = l1b[j];
    for (int c = 0; c < NCMT; ++c) a = fmaf(sbuf[c], l1w[j * NCMT + c], a);
    z1[j] = fmaxf(a, 0.f);
  }
  __syncthreads();
  if (t < NCLS) {
    float a = l2b[t];
    for (int j = 0; j < HFC; ++j) a = fmaf(z1[j], l2w[t * HFC + j], a);
    z2[t] = a;
  }
  __syncthreads();
  if (t == 0) {
    float mx = z2[0];
    for (int k = 1; k < NCLS; ++k) mx = fmaxf(mx, z2[k]);
    float se = 0.f;
    for (int k = 0; k < NCLS; ++k) se += expf(z2[k] - mx);
    float lse = mx + logf(se);
    for (int k = 0; k < NCLS; ++k) out[b * NCLS + k] = z2[k] - lse;
  }
}

extern "C" void kernel_launch(void* const* d_in, const int* in_sizes, int n_in,
                              void* d_out, int out_size, void* d_ws, size_t ws_size,
                              hipStream_t stream) {
  const float* x   = (const float*)d_in[0];
  const int*  ei   = (const int*)d_in[2];
  const int*  row  = (const int*)d_in[3];
  const int*  col  = (const int*)d_in[4];
  const float* W1  = (const float*)d_in[5];
  const float* b1  = (const float*)d_in[6];
  const float* W2  = (const float*)d_in[7];
  const float* b2  = (const float*)d_in[8];
  const float* W3  = (const float*)d_in[9];
  const float* b3  = (const float*)d_in[10];
  const float* fcw = (const float*)d_in[11];
  const float* fcb = (const float*)d_in[12];
  const float* l1w = (const float*)d_in[13];
  const float* l1b = (const float*)d_in[14];
  const float* l2w = (const float*)d_in[15];
  const float* l2b = (const float*)d_in[16];

  const int BS   = in_sizes[1];               // 8
  const int H    = in_sizes[6];               // 64
  const int F    = in_sizes[5] / H;           // 64
  const int N    = in_sizes[0] / (BS * F);    // 15135
  const int E    = in_sizes[2] / 2;           // 300000
  const int R    = in_sizes[3];               // 40000
  const int HFC  = in_sizes[14];              // 200
  const int NCMT = in_sizes[13] / HFC;        // 400
  const int NCLS = in_sizes[16];              // 2
  const int L    = in_sizes[11] / H;          // 3

  // workspace carve-out (256B aligned)
  char* p = (char*)d_ws;
  auto alloc = [&](size_t bytes) {
    void* r = (void*)p;
    p += (bytes + 255) & ~(size_t)255;
    return r;
  };
  size_t nAlign = ((size_t)N * 4 + 255) & ~(size_t)255;
  int*   degi      = (int*)alloc((size_t)N * 4);
  int*   cursor    = (int*)alloc((size_t)N * 4);   // contiguous with degi
  int*   row_start = (int*)alloc((size_t)(N + 1) * 4);
  unsigned short* csr = (unsigned short*)alloc((size_t)(E + 8) * 2);  // u16 + pad
  float* dinv      = (float*)alloc((size_t)N * 4);
  float* q         = (float*)alloc((size_t)N * BS * 4);
  size_t sAlign = ((size_t)NCMT * BS * 4 + 255) & ~(size_t)255;
  float* s_sum     = (float*)alloc((size_t)NCMT * BS * 4);
  float* cntc      = (float*)alloc((size_t)NCMT * 4);  // contiguous with s_sum
  float* m         = (float*)alloc((size_t)N * BS * H * 4);
  float* hA        = (float*)alloc((size_t)N * BS * H * 4);
  float* hB        = (float*)alloc((size_t)N * BS * H * 4);

  // merged memsets over adjacent regions
  (void)hipMemsetAsync(degi, 0, nAlign + (size_t)N * 4, stream);          // degi + cursor
  (void)hipMemsetAsync(csr + E, 0, 16, stream);                           // prefetch pad
  (void)hipMemsetAsync(s_sum, 0, sAlign + (size_t)NCMT * 4, stream);      // s_sum + cntc

  const int* e_src = ei;
  const int* e_dst = ei + E;

  count_kernel<<<(E + 255) / 256, 256, 0, stream>>>(e_dst, degi, E);
  prefix_kernel<<<1, 1024, 0, stream>>>(degi, row_start, N);
  fill_kernel<<<(E + 255) / 256, 256, 0, stream>>>(e_src, e_dst, row_start, cursor, csr, E);
  dinv_kernel<<<(N + 255) / 256, 256, 0, stream>>>(degi, dinv, N);

  int lin_grid = ((N + 127) / 128) * BS;  // 2 row-tiles per block
  int agg_grid = ((N + 15) / 16) * BS;    // 4 waves x 4 nodes = 16 nodes/block
  int agg_threads = 256;

  // layer 1 (x is fp32 [b][n][f])
  linear_kernel<<<lin_grid, 256, 0, stream>>>(x, W1, dinv, m, N, BS);
  agg_kernel<true><<<agg_grid, agg_threads, 0, stream>>>(m, dinv, b1, row_start, csr, hA, q, fcw, 0, L, N, BS);
  // layer 2
  linear_kernel<<<lin_grid, 256, 0, stream>>>(hA, W2, dinv, m, N, BS);
  agg_kernel<true><<<agg_grid, agg_threads, 0, stream>>>(m, dinv, b2, row_start, csr, hB, q, fcw, 1, L, N, BS);
  // layer 3 — hout is dead (only q survives), skip the store
  linear_kernel<<<lin_grid, 256, 0, stream>>>(hB, W3, dinv, m, N, BS);
  agg_kernel<false><<<agg_grid, agg_threads, 0, stream>>>(m, dinv, b3, row_start, csr, nullptr, q, fcw, 2, L, N, BS);

  pathway_kernel<<<((size_t)R * BS + 255) / 256, 256, 0, stream>>>(row, col, q, s_sum, cntc, R, N, BS);
  head_kernel<<<BS, 256, 0, stream>>>(s_sum, cntc, fcb, l1w, l1b, l2w, l2b,
                                      (float*)d_out, NCMT, HFC, NCLS, BS);
}